// Round 1
// baseline (996.826 us; speedup 1.0000x reference)
//
#include <hip/hip_runtime.h>
#include <hip/hip_bf16.h>
#include <math.h>

#define T_TOK 8192
#define DMODEL 1024
#define FFN 4096
#define NEXP 8
#define NSLOT (T_TOK * 2)
#define MAXT 160  // >= sum ceil(count_e/128) worst case = 136

typedef _Float16 f16;
typedef _Float16 half8 __attribute__((ext_vector_type(8)));
typedef float f32x4 __attribute__((ext_vector_type(4)));
typedef unsigned int u32;

__device__ __forceinline__ void gll16(const void* g, void* l) {
  __builtin_amdgcn_global_load_lds(
      (const __attribute__((address_space(1))) u32*)g,
      (__attribute__((address_space(3))) u32*)l, 16, 0, 0);
}

__device__ __forceinline__ float gelu_exact(float v) {
  return 0.5f * v * (1.0f + erff(v * 0.70710678118654752f));
}

// ---------------- router: logits -> top2 -> renormalized weights ----------
__global__ __launch_bounds__(256) void router_k(
    const float* __restrict__ x, const float* __restrict__ Wr,
    int* __restrict__ sel_e, float* __restrict__ sel_w, int* __restrict__ counts) {
  int t = blockIdx.x * 4 + (threadIdx.x >> 6);
  int lane = threadIdx.x & 63;
  const float* xp = x + (size_t)t * DMODEL;
  float p[NEXP];
#pragma unroll
  for (int e = 0; e < NEXP; e++) p[e] = 0.f;
#pragma unroll
  for (int i = 0; i < DMODEL / 64; i++) {
    float xv = xp[lane + i * 64];
#pragma unroll
    for (int e = 0; e < NEXP; e++) p[e] += xv * Wr[e * DMODEL + lane + i * 64];
  }
#pragma unroll
  for (int off = 32; off; off >>= 1) {
#pragma unroll
    for (int e = 0; e < NEXP; e++) p[e] += __shfl_xor(p[e], off);
  }
  if (lane == 0) {
    float l0 = -1e30f, l1 = -1e30f;
    int e0 = 0, e1 = 1;
#pragma unroll
    for (int e = 0; e < NEXP; e++) {
      if (p[e] > l0) { l1 = l0; e1 = e0; l0 = p[e]; e0 = e; }
      else if (p[e] > l1) { l1 = p[e]; e1 = e; }
    }
    float r = expf(l1 - l0);          // <= 1
    float inv = 1.f / (1.f + r);
    sel_e[t * 2] = e0;     sel_w[t * 2] = inv;
    sel_e[t * 2 + 1] = e1; sel_w[t * 2 + 1] = r * inv;
    atomicAdd(&counts[e0], 1);
    atomicAdd(&counts[e1], 1);
  }
}

// ---------------- schedule: offsets + tile table (single thread, tiny) -----
__global__ void sched_k(int* meta) {
  int* counts = meta;
  int* fill = meta + 64;
  int* offs = meta + 128;
  int* tE = meta + 256;
  int* tR0 = meta + 512;
  int* tRows = meta + 768;
  int off = 0, nt = 0;
  for (int e = 0; e < NEXP; e++) {
    offs[e] = off;
    fill[e] = 0;
    int c = counts[e];
    for (int t0 = 0; t0 < c; t0 += 128) {
      tE[nt] = e; tR0[nt] = off + t0; tRows[nt] = min(128, c - t0); nt++;
    }
    off += c;
  }
  offs[NEXP] = off;
  for (; nt < MAXT; nt++) tE[nt] = -1;
}

// ---------------- scatter tokens into expert-sorted row list --------------
__global__ __launch_bounds__(256) void scatter_k(
    const int* __restrict__ sel_e, const float* __restrict__ sel_w,
    const int* __restrict__ offs, int* fill,
    int* __restrict__ row_tok, float* __restrict__ row_w) {
  int s = blockIdx.x * 256 + threadIdx.x;
  int e = sel_e[s];
  int pos = atomicAdd(&fill[e], 1);
  int r = offs[e] + pos;
  row_tok[r] = s >> 1;
  row_w[r] = sel_w[s];
}

// ---------------- f32 -> f16 elementwise (x) ------------------------------
__global__ __launch_bounds__(256) void cvtx_k(const float* __restrict__ x,
                                              f16* __restrict__ xh) {
  int i = blockIdx.x * 256 + threadIdx.x;  // 8 elems per thread
  const float4* src = (const float4*)x;
  float4 a = src[i * 2], b = src[i * 2 + 1];
  half8 h;
  h[0] = (f16)a.x; h[1] = (f16)a.y; h[2] = (f16)a.z; h[3] = (f16)a.w;
  h[4] = (f16)b.x; h[5] = (f16)b.y; h[6] = (f16)b.z; h[7] = (f16)b.w;
  ((half8*)xh)[i] = h;
}

// ---------------- transpose + convert: out[e][c][r] = (f16) in[e][r][c] ----
__global__ __launch_bounds__(256) void transq_k(const float* __restrict__ in,
                                                f16* __restrict__ out, int R, int C) {
  __shared__ float tile[32][33];
  int e = blockIdx.z;
  const float* ip = in + (size_t)e * R * C;
  f16* op = out + (size_t)e * R * C;
  int c0 = blockIdx.x * 32, r0 = blockIdx.y * 32;
  int tx = threadIdx.x & 31, ty = threadIdx.x >> 5;
#pragma unroll
  for (int j = 0; j < 4; j++)
    tile[ty + j * 8][tx] = ip[(size_t)(r0 + ty + j * 8) * C + (c0 + tx)];
  __syncthreads();
#pragma unroll
  for (int j = 0; j < 4; j++)
    op[(size_t)(c0 + ty + j * 8) * R + (r0 + tx)] = (f16)tile[tx][ty + j * 8];
}

// ---------------- GEMM1: H = gelu(Xg @ W_in + b_in), fp16 out -------------
// A: gathered Xh rows [128 x 1024]; B: Wih[e] in [F][D] (N-major) layout.
__global__ __launch_bounds__(256) void gemm1_k(
    const f16* __restrict__ Xh, const f16* __restrict__ Wt,
    const float* __restrict__ b_in, f16* __restrict__ H,
    const int* __restrict__ meta) {
  int tm = blockIdx.x;
  int e = (meta + 256)[tm];
  if (e < 0) return;
  int row0 = (meta + 512)[tm];
  int nrows = (meta + 768)[tm];
  const int* row_tok = meta + 1024 + 2 * NSLOT;
  int n0 = blockIdx.y * 128;

  __shared__ f16 smA[128 * 32];
  __shared__ f16 smB[128 * 32];

  int tid = threadIdx.x, lane = tid & 63, wid = tid >> 6;
  int wm = (wid >> 1) * 64, wn = (wid & 1) * 64;

  int ar = tid >> 2, koff = (tid & 3) * 8;
  int r0g = min(row0 + ar, NSLOT - 1);
  int r1g = min(row0 + 64 + ar, NSLOT - 1);
  const f16* gA0 = Xh + (size_t)row_tok[r0g] * DMODEL + koff;
  const f16* gA1 = Xh + (size_t)row_tok[r1g] * DMODEL + koff;
  const f16* gB0 = Wt + ((size_t)e * FFN + n0 + ar) * DMODEL + koff;
  const f16* gB1 = Wt + ((size_t)e * FFN + n0 + 64 + ar) * DMODEL + koff;
  char* lA0 = (char*)smA + tid * 16;
  char* lA1 = (char*)smA + (tid + 256) * 16;
  char* lB0 = (char*)smB + tid * 16;
  char* lB1 = (char*)smB + (tid + 256) * 16;

  f32x4 acc[4][4];
#pragma unroll
  for (int m = 0; m < 4; m++)
#pragma unroll
    for (int n = 0; n < 4; n++) acc[m][n] = (f32x4)0.f;

  for (int k = 0; k < DMODEL; k += 32) {
    gll16(gA0 + k, lA0);
    gll16(gA1 + k, lA1);
    gll16(gB0 + k, lB0);
    gll16(gB1 + k, lB1);
    __syncthreads();  // drains vmcnt -> LDS ready
    half8 a[4], b[4];
#pragma unroll
    for (int m = 0; m < 4; m++)
      a[m] = *(const half8*)(smA + (wm + m * 16 + (lane & 15)) * 32 + (lane >> 4) * 8);
#pragma unroll
    for (int n = 0; n < 4; n++)
      b[n] = *(const half8*)(smB + (wn + n * 16 + (lane & 15)) * 32 + (lane >> 4) * 8);
#pragma unroll
    for (int m = 0; m < 4; m++)
#pragma unroll
      for (int n = 0; n < 4; n++)
        acc[m][n] = __builtin_amdgcn_mfma_f32_16x16x32_f16(a[m], b[n], acc[m][n], 0, 0, 0);
    __syncthreads();  // all reads done before next stage overwrites
  }

  int cl = lane & 15, rb = (lane >> 4) * 4;
#pragma unroll
  for (int n = 0; n < 4; n++) {
    int c = n0 + wn + n * 16 + cl;
    float bias = b_in[e * FFN + c];
#pragma unroll
    for (int m = 0; m < 4; m++) {
      int rloc = wm + m * 16 + rb;
#pragma unroll
      for (int j = 0; j < 4; j++) {
        if (rloc + j < nrows) {
          float v = acc[m][n][j] + bias;
          H[(size_t)(row0 + rloc + j) * FFN + c] = (f16)gelu_exact(v);
        }
      }
    }
  }
}

// ---------------- GEMM2: out[tok] += w * (H @ W_out + b_out) --------------
// A: H rows [128 x 4096]; B: Woh[e] in [D][F] (N-major) layout.
__global__ __launch_bounds__(256) void gemm2_k(
    const f16* __restrict__ H, const f16* __restrict__ Wt,
    const float* __restrict__ b_out, float* __restrict__ out,
    const int* __restrict__ meta) {
  int tm = blockIdx.x;
  int e = (meta + 256)[tm];
  if (e < 0) return;
  int row0 = (meta + 512)[tm];
  int nrows = (meta + 768)[tm];
  const int* row_tok = meta + 1024 + 2 * NSLOT;
  const float* row_w = (const float*)(meta + 1024 + 3 * NSLOT);
  int n0 = blockIdx.y * 128;

  __shared__ f16 smA[128 * 32];
  __shared__ f16 smB[128 * 32];

  int tid = threadIdx.x, lane = tid & 63, wid = tid >> 6;
  int wm = (wid >> 1) * 64, wn = (wid & 1) * 64;

  int ar = tid >> 2, koff = (tid & 3) * 8;
  size_t rA0 = (size_t)min(row0 + ar, NSLOT - 1);
  size_t rA1 = (size_t)min(row0 + 64 + ar, NSLOT - 1);
  const f16* gA0 = H + rA0 * FFN + koff;
  const f16* gA1 = H + rA1 * FFN + koff;
  const f16* gB0 = Wt + ((size_t)e * DMODEL + n0 + ar) * FFN + koff;
  const f16* gB1 = Wt + ((size_t)e * DMODEL + n0 + 64 + ar) * FFN + koff;
  char* lA0 = (char*)smA + tid * 16;
  char* lA1 = (char*)smA + (tid + 256) * 16;
  char* lB0 = (char*)smB + tid * 16;
  char* lB1 = (char*)smB + (tid + 256) * 16;

  f32x4 acc[4][4];
#pragma unroll
  for (int m = 0; m < 4; m++)
#pragma unroll
    for (int n = 0; n < 4; n++) acc[m][n] = (f32x4)0.f;

  for (int k = 0; k < FFN; k += 32) {
    gll16(gA0 + k, lA0);
    gll16(gA1 + k, lA1);
    gll16(gB0 + k, lB0);
    gll16(gB1 + k, lB1);
    __syncthreads();
    half8 a[4], b[4];
#pragma unroll
    for (int m = 0; m < 4; m++)
      a[m] = *(const half8*)(smA + (wm + m * 16 + (lane & 15)) * 32 + (lane >> 4) * 8);
#pragma unroll
    for (int n = 0; n < 4; n++)
      b[n] = *(const half8*)(smB + (wn + n * 16 + (lane & 15)) * 32 + (lane >> 4) * 8);
#pragma unroll
    for (int m = 0; m < 4; m++)
#pragma unroll
      for (int n = 0; n < 4; n++)
        acc[m][n] = __builtin_amdgcn_mfma_f32_16x16x32_f16(a[m], b[n], acc[m][n], 0, 0, 0);
    __syncthreads();
  }

  int cl = lane & 15, rb = (lane >> 4) * 4;
#pragma unroll
  for (int n = 0; n < 4; n++) {
    int c = n0 + wn + n * 16 + cl;
    float bias = b_out[e * DMODEL + c];
#pragma unroll
    for (int m = 0; m < 4; m++) {
      int rloc = wm + m * 16 + rb;
#pragma unroll
      for (int j = 0; j < 4; j++) {
        if (rloc + j < nrows) {
          int rg = row0 + rloc + j;
          int tok = row_tok[rg];
          float w = row_w[rg];
          atomicAdd(&out[(size_t)tok * DMODEL + c], w * (acc[m][n][j] + bias));
        }
      }
    }
  }
}

// ---------------- fallback (small workspace): fused f32, correct but slow --
__global__ __launch_bounds__(256) void naive_k(
    const float* __restrict__ x, const float* __restrict__ W_in,
    const float* __restrict__ b_in, const float* __restrict__ W_out,
    const float* __restrict__ b_out, const int* __restrict__ sel_e,
    const float* __restrict__ sel_w, float* __restrict__ out) {
  int s = blockIdx.x;
  int t = s >> 1;
  int e = sel_e[s];
  float w = sel_w[s];
  __shared__ float xs[DMODEL];
  __shared__ float hs[FFN];
  int tid = threadIdx.x;
  for (int d = tid; d < DMODEL; d += 256) xs[d] = x[(size_t)t * DMODEL + d];
  __syncthreads();
  for (int f = tid; f < FFN; f += 256) {
    float a = b_in[e * FFN + f];
    const float* wp = W_in + (size_t)e * DMODEL * FFN + f;
    for (int d = 0; d < DMODEL; d++) a += xs[d] * wp[(size_t)d * FFN];
    hs[f] = gelu_exact(a);
  }
  __syncthreads();
  for (int d = tid; d < DMODEL; d += 256) {
    float a = b_out[e * DMODEL + d];
    const float* wp = W_out + (size_t)e * FFN * DMODEL + d;
    for (int f = 0; f < FFN; f++) a += hs[f] * wp[(size_t)f * DMODEL];
    atomicAdd(&out[(size_t)t * DMODEL + d], w * a);
  }
}

extern "C" void kernel_launch(void* const* d_in, const int* in_sizes, int n_in,
                              void* d_out, int out_size, void* d_ws, size_t ws_size,
                              hipStream_t stream) {
  const float* residual = (const float*)d_in[0];
  const float* W_router = (const float*)d_in[1];
  const float* W_in = (const float*)d_in[2];
  const float* b_in = (const float*)d_in[3];
  const float* W_out = (const float*)d_in[4];
  const float* b_out = (const float*)d_in[5];
  float* out = (float*)d_out;

  char* ws = (char*)d_ws;
  int* meta = (int*)ws;  // 1 MB reserved for counters/schedule/lists
  size_t off = (size_t)1 << 20;
  f16* Xh = (f16*)(ws + off); off += (size_t)T_TOK * DMODEL * 2;       // 16 MB
  f16* Wih = (f16*)(ws + off); off += (size_t)NEXP * DMODEL * FFN * 2; // 64 MB
  f16* Woh = (f16*)(ws + off); off += (size_t)NEXP * DMODEL * FFN * 2; // 64 MB
  f16* H = (f16*)(ws + off); off += (size_t)NSLOT * FFN * 2;           // 128 MB
  bool fast = ws_size >= off;

  int* sel_e = meta + 1024;
  float* sel_w = (float*)(meta + 1024 + NSLOT);
  int* row_tok = meta + 1024 + 2 * NSLOT;
  float* row_w = (float*)(meta + 1024 + 3 * NSLOT);

  hipMemsetAsync(meta, 0, 4096, stream);                              // counts
  hipMemsetAsync(d_out, 0, (size_t)out_size * sizeof(float), stream); // output acc

  router_k<<<T_TOK / 4, 256, 0, stream>>>(residual, W_router, sel_e, sel_w, meta);

  if (fast) {
    cvtx_k<<<(T_TOK * DMODEL / 8) / 256, 256, 0, stream>>>(residual, Xh);
    transq_k<<<dim3(FFN / 32, DMODEL / 32, NEXP), 256, 0, stream>>>(W_in, Wih, DMODEL, FFN);
    transq_k<<<dim3(DMODEL / 32, FFN / 32, NEXP), 256, 0, stream>>>(W_out, Woh, FFN, DMODEL);
    sched_k<<<1, 1, 0, stream>>>(meta);
    scatter_k<<<NSLOT / 256, 256, 0, stream>>>(sel_e, sel_w, meta + 128, meta + 64,
                                               row_tok, row_w);
    gemm1_k<<<dim3(MAXT, FFN / 128), 256, 0, stream>>>(Xh, Wih, b_in, H, meta);
    gemm2_k<<<dim3(MAXT, DMODEL / 128), 256, 0, stream>>>(H, Woh, b_out, out, meta);
  } else {
    naive_k<<<NSLOT, 256, 0, stream>>>(residual, W_in, b_in, W_out, b_out,
                                       sel_e, sel_w, out);
  }
}

// Round 2
// 832.616 us; speedup vs baseline: 1.1972x; 1.1972x over previous
//
#include <hip/hip_runtime.h>
#include <hip/hip_bf16.h>
#include <math.h>

#define T_TOK 8192
#define DMODEL 1024
#define FFN 4096
#define NEXP 8
#define NSLOT (T_TOK * 2)
#define MAXT 160  // >= sum ceil(count_e/128); worst case 136

typedef _Float16 f16;
typedef _Float16 half8 __attribute__((ext_vector_type(8)));
typedef float f32x4 __attribute__((ext_vector_type(4)));
typedef unsigned int u32;

__device__ __forceinline__ void gll16(const void* g, void* l) {
  __builtin_amdgcn_global_load_lds(
      (const __attribute__((address_space(1))) u32*)g,
      (__attribute__((address_space(3))) u32*)l, 16, 0, 0);
}

__device__ __forceinline__ float gelu_exact(float v) {
  return 0.5f * v * (1.0f + erff(v * 0.70710678118654752f));
}

// ---------------- router: logits -> top2 -> renormalized weights ----------
__global__ __launch_bounds__(256) void router_k(
    const float* __restrict__ x, const float* __restrict__ Wr,
    int* __restrict__ sel_e, float* __restrict__ sel_w, int* __restrict__ counts) {
  int t = blockIdx.x * 4 + (threadIdx.x >> 6);
  int lane = threadIdx.x & 63;
  const float* xp = x + (size_t)t * DMODEL;
  float p[NEXP];
#pragma unroll
  for (int e = 0; e < NEXP; e++) p[e] = 0.f;
#pragma unroll
  for (int i = 0; i < DMODEL / 64; i++) {
    float xv = xp[lane + i * 64];
#pragma unroll
    for (int e = 0; e < NEXP; e++) p[e] += xv * Wr[e * DMODEL + lane + i * 64];
  }
#pragma unroll
  for (int off = 32; off; off >>= 1) {
#pragma unroll
    for (int e = 0; e < NEXP; e++) p[e] += __shfl_xor(p[e], off);
  }
  if (lane == 0) {
    float l0 = -1e30f, l1 = -1e30f;
    int e0 = 0, e1 = 1;
#pragma unroll
    for (int e = 0; e < NEXP; e++) {
      if (p[e] > l0) { l1 = l0; e1 = e0; l0 = p[e]; e0 = e; }
      else if (p[e] > l1) { l1 = p[e]; e1 = e; }
    }
    float r = expf(l1 - l0);          // <= 1
    float inv = 1.f / (1.f + r);
    sel_e[t * 2] = e0;     sel_w[t * 2] = inv;
    sel_e[t * 2 + 1] = e1; sel_w[t * 2 + 1] = r * inv;
    atomicAdd(&counts[e0], 1);
    atomicAdd(&counts[e1], 1);
  }
}

// ---------------- schedule: offsets + tile table (single thread, tiny) -----
__global__ void sched_k(int* meta) {
  int* counts = meta;
  int* fill = meta + 64;
  int* offs = meta + 128;
  int* tE = meta + 256;
  int* tR0 = meta + 512;
  int* tRows = meta + 768;
  int off = 0, nt = 0;
  for (int e = 0; e < NEXP; e++) {
    offs[e] = off;
    fill[e] = 0;
    int c = counts[e];
    for (int t0 = 0; t0 < c; t0 += 128) {
      tE[nt] = e; tR0[nt] = off + t0; tRows[nt] = min(128, c - t0); nt++;
    }
    off += c;
  }
  offs[NEXP] = off;
  for (; nt < MAXT; nt++) tE[nt] = -1;
}

// ---------------- scatter tokens into expert-sorted row list --------------
__global__ __launch_bounds__(256) void scatter_k(
    const int* __restrict__ sel_e, const float* __restrict__ sel_w,
    const int* __restrict__ offs, int* fill,
    int* __restrict__ row_tok, float* __restrict__ row_w) {
  int s = blockIdx.x * 256 + threadIdx.x;
  int e = sel_e[s];
  int pos = atomicAdd(&fill[e], 1);
  int r = offs[e] + pos;
  row_tok[r] = s >> 1;
  row_w[r] = sel_w[s];
}

// ---------------- f32 -> f16 elementwise (x) ------------------------------
__global__ __launch_bounds__(256) void cvtx_k(const float* __restrict__ x,
                                              f16* __restrict__ xh) {
  int i = blockIdx.x * 256 + threadIdx.x;  // 8 elems per thread
  const float4* src = (const float4*)x;
  float4 a = src[i * 2], b = src[i * 2 + 1];
  half8 h;
  h[0] = (f16)a.x; h[1] = (f16)a.y; h[2] = (f16)a.z; h[3] = (f16)a.w;
  h[4] = (f16)b.x; h[5] = (f16)b.y; h[6] = (f16)b.z; h[7] = (f16)b.w;
  ((half8*)xh)[i] = h;
}

// ---------------- transpose + convert: out[e][c][r] = (f16) in[e][r][c] ----
__global__ __launch_bounds__(256) void transq_k(const float* __restrict__ in,
                                                f16* __restrict__ out, int R, int C) {
  __shared__ float tile[32][33];
  int e = blockIdx.z;
  const float* ip = in + (size_t)e * R * C;
  f16* op = out + (size_t)e * R * C;
  int c0 = blockIdx.x * 32, r0 = blockIdx.y * 32;
  int tx = threadIdx.x & 31, ty = threadIdx.x >> 5;
#pragma unroll
  for (int j = 0; j < 4; j++)
    tile[ty + j * 8][tx] = ip[(size_t)(r0 + ty + j * 8) * C + (c0 + tx)];
  __syncthreads();
#pragma unroll
  for (int j = 0; j < 4; j++)
    op[(size_t)(c0 + ty + j * 8) * R + (r0 + tx)] = (f16)tile[tx][ty + j * 8];
}

// ============ GEMM1: H = gelu(Xg @ W_in + b_in), fp16 out =================
// 3-slot LDS ring, 2-deep prefetch, counted vmcnt, raw s_barrier.
// grid 1D = MAXT*32; XCD-bijective swizzle; n-slow/tm-fast decode.
__global__ __launch_bounds__(256) void gemm1_k(
    const f16* __restrict__ Xh, const f16* __restrict__ Wt,
    const float* __restrict__ b_in, f16* __restrict__ H,
    const int* __restrict__ meta) {
  int G = gridDim.x;
  int wg = ((blockIdx.x & 7) * (G >> 3)) + (blockIdx.x >> 3);  // bijective, G%8==0
  int tm = wg % MAXT;        // fast: consecutive same-XCD blocks share B panel
  int n0 = (wg / MAXT) * 128;

  int e = (meta + 256)[tm];
  if (e < 0) return;
  int row0 = (meta + 512)[tm];
  int nrows = (meta + 768)[tm];
  const int* row_tok = meta + 1024 + 2 * NSLOT;

  __shared__ f16 ldsbuf[24576];  // 48 KB: A slots @0/8/16 KB, B slots @24/32/40 KB

  int tid = threadIdx.x, lane = tid & 63, wid = tid >> 6;
  int wm = (wid >> 1) * 64, wn = (wid & 1) * 64;

  int ar = tid >> 2, koff = (tid & 3) * 8;
  int r0g = min(row0 + ar, NSLOT - 1);
  int r1g = min(row0 + 64 + ar, NSLOT - 1);
  const f16* gA0 = Xh + (size_t)row_tok[r0g] * DMODEL + koff;
  const f16* gA1 = Xh + (size_t)row_tok[r1g] * DMODEL + koff;
  const f16* gB0 = Wt + ((size_t)e * FFN + n0 + ar) * DMODEL + koff;
  const f16* gB1 = Wt + ((size_t)e * FFN + n0 + 64 + ar) * DMODEL + koff;
  char* lbase = (char*)ldsbuf;

  f32x4 acc[4][4];
#pragma unroll
  for (int m = 0; m < 4; m++)
#pragma unroll
    for (int n = 0; n < 4; n++) acc[m][n] = (f32x4)0.f;

  auto stage = [&](int slot, int t) {
    int k = t * 32;
    gll16(gA0 + k, lbase + slot * 8192 + tid * 16);
    gll16(gA1 + k, lbase + slot * 8192 + 4096 + tid * 16);
    gll16(gB0 + k, lbase + 24576 + slot * 8192 + tid * 16);
    gll16(gB1 + k, lbase + 24576 + slot * 8192 + 4096 + tid * 16);
  };
  auto compute = [&](int slot) {
    const f16* bA = ldsbuf + slot * 4096;
    const f16* bB = ldsbuf + 12288 + slot * 4096;
    half8 a[4], b[4];
#pragma unroll
    for (int m = 0; m < 4; m++)
      a[m] = *(const half8*)(bA + (wm + m * 16 + (lane & 15)) * 32 + (lane >> 4) * 8);
#pragma unroll
    for (int n = 0; n < 4; n++)
      b[n] = *(const half8*)(bB + (wn + n * 16 + (lane & 15)) * 32 + (lane >> 4) * 8);
#pragma unroll
    for (int m = 0; m < 4; m++)
#pragma unroll
      for (int n = 0; n < 4; n++)
        acc[m][n] = __builtin_amdgcn_mfma_f32_16x16x32_f16(a[m], b[n], acc[m][n], 0, 0, 0);
  };

  const int NT = DMODEL / 32;  // 32
  stage(0, 0);
  stage(1, 1);
  for (int t = 0; t < NT - 2; ++t) {
    stage((t + 2) % 3, t + 2);
    asm volatile("s_waitcnt vmcnt(8)" ::: "memory");  // tile-t staging done
    __builtin_amdgcn_s_barrier();
    compute(t % 3);
    asm volatile("s_waitcnt lgkmcnt(0)" ::: "memory");  // my ds_reads retired
    __builtin_amdgcn_s_barrier();
  }
  asm volatile("s_waitcnt vmcnt(4)" ::: "memory");
  __builtin_amdgcn_s_barrier();
  compute((NT - 2) % 3);
  asm volatile("s_waitcnt lgkmcnt(0)" ::: "memory");
  __builtin_amdgcn_s_barrier();
  asm volatile("s_waitcnt vmcnt(0)" ::: "memory");
  __builtin_amdgcn_s_barrier();
  compute((NT - 1) % 3);
  asm volatile("s_waitcnt lgkmcnt(0)" ::: "memory");
  __builtin_amdgcn_s_barrier();

  // Epilogue: bias+gelu -> f16 repack tile [128][128] in LDS -> float4 stores
  int cl = lane & 15, rb = (lane >> 4) * 4;
#pragma unroll
  for (int n = 0; n < 4; n++) {
    int c = n0 + wn + n * 16 + cl;
    float bias = b_in[e * FFN + c];
#pragma unroll
    for (int m = 0; m < 4; m++) {
      int rloc = wm + m * 16 + rb;
#pragma unroll
      for (int j = 0; j < 4; j++) {
        float v = acc[m][n][j] + bias;
        ldsbuf[(rloc + j) * 128 + (wn + n * 16 + cl)] = (f16)gelu_exact(v);
      }
    }
  }
  __syncthreads();
#pragma unroll
  for (int p = 0; p < 8; ++p) {
    int idx = tid + p * 256;     // 2048 16B-chunks
    int r = idx >> 4;
    int cb = (idx & 15) * 8;
    if (r < nrows)
      *(float4*)(H + (size_t)(row0 + r) * FFN + n0 + cb) =
          *(const float4*)(ldsbuf + r * 128 + cb);
  }
}

// ============ GEMM2: out[tok] += w * (H @ W_out + b_out) ==================
// grid 1D = MAXT*8; XCD-bijective swizzle; tm-slow/n-fast decode (A L2-reuse,
// H streamed once; Woh served from L3).
__global__ __launch_bounds__(256) void gemm2_k(
    const f16* __restrict__ H, const f16* __restrict__ Wt,
    const float* __restrict__ b_out, float* __restrict__ out,
    const int* __restrict__ meta) {
  int G = gridDim.x;
  int wg = ((blockIdx.x & 7) * (G >> 3)) + (blockIdx.x >> 3);
  int tm = wg >> 3;          // slow
  int n0 = (wg & 7) * 128;   // fast: A-panel reused across 8 consecutive blocks

  int e = (meta + 256)[tm];
  if (e < 0) return;
  int row0 = (meta + 512)[tm];
  int nrows = (meta + 768)[tm];
  const int* row_tok = meta + 1024 + 2 * NSLOT;
  const float* row_w = (const float*)(meta + 1024 + 3 * NSLOT);

  __shared__ f16 ldsbuf[24576];

  int tid = threadIdx.x, lane = tid & 63, wid = tid >> 6;
  int wm = (wid >> 1) * 64, wn = (wid & 1) * 64;

  int ar = tid >> 2, koff = (tid & 3) * 8;
  size_t rA0 = (size_t)min(row0 + ar, NSLOT - 1);
  size_t rA1 = (size_t)min(row0 + 64 + ar, NSLOT - 1);
  const f16* gA0 = H + rA0 * FFN + koff;
  const f16* gA1 = H + rA1 * FFN + koff;
  const f16* gB0 = Wt + ((size_t)e * DMODEL + n0 + ar) * FFN + koff;
  const f16* gB1 = Wt + ((size_t)e * DMODEL + n0 + 64 + ar) * FFN + koff;
  char* lbase = (char*)ldsbuf;

  f32x4 acc[4][4];
#pragma unroll
  for (int m = 0; m < 4; m++)
#pragma unroll
    for (int n = 0; n < 4; n++) acc[m][n] = (f32x4)0.f;

  auto stage = [&](int slot, int t) {
    int k = t * 32;
    gll16(gA0 + k, lbase + slot * 8192 + tid * 16);
    gll16(gA1 + k, lbase + slot * 8192 + 4096 + tid * 16);
    gll16(gB0 + k, lbase + 24576 + slot * 8192 + tid * 16);
    gll16(gB1 + k, lbase + 24576 + slot * 8192 + 4096 + tid * 16);
  };
  auto compute = [&](int slot) {
    const f16* bA = ldsbuf + slot * 4096;
    const f16* bB = ldsbuf + 12288 + slot * 4096;
    half8 a[4], b[4];
#pragma unroll
    for (int m = 0; m < 4; m++)
      a[m] = *(const half8*)(bA + (wm + m * 16 + (lane & 15)) * 32 + (lane >> 4) * 8);
#pragma unroll
    for (int n = 0; n < 4; n++)
      b[n] = *(const half8*)(bB + (wn + n * 16 + (lane & 15)) * 32 + (lane >> 4) * 8);
#pragma unroll
    for (int m = 0; m < 4; m++)
#pragma unroll
      for (int n = 0; n < 4; n++)
        acc[m][n] = __builtin_amdgcn_mfma_f32_16x16x32_f16(a[m], b[n], acc[m][n], 0, 0, 0);
  };

  const int NT = FFN / 32;  // 128
  stage(0, 0);
  stage(1, 1);
  for (int t = 0; t < NT - 2; ++t) {
    stage((t + 2) % 3, t + 2);
    asm volatile("s_waitcnt vmcnt(8)" ::: "memory");
    __builtin_amdgcn_s_barrier();
    compute(t % 3);
    asm volatile("s_waitcnt lgkmcnt(0)" ::: "memory");
    __builtin_amdgcn_s_barrier();
  }
  asm volatile("s_waitcnt vmcnt(4)" ::: "memory");
  __builtin_amdgcn_s_barrier();
  compute((NT - 2) % 3);
  asm volatile("s_waitcnt lgkmcnt(0)" ::: "memory");
  __builtin_amdgcn_s_barrier();
  asm volatile("s_waitcnt vmcnt(0)" ::: "memory");
  __builtin_amdgcn_s_barrier();
  compute((NT - 1) % 3);

  int cl = lane & 15, rb = (lane >> 4) * 4;
#pragma unroll
  for (int n = 0; n < 4; n++) {
    int c = n0 + wn + n * 16 + cl;
    float bias = b_out[e * DMODEL + c];
#pragma unroll
    for (int m = 0; m < 4; m++) {
      int rloc = wm + m * 16 + rb;
#pragma unroll
      for (int j = 0; j < 4; j++) {
        if (rloc + j < nrows) {
          int rg = row0 + rloc + j;
          int tok = row_tok[rg];
          float w = row_w[rg];
          atomicAdd(&out[(size_t)tok * DMODEL + c], w * (acc[m][n][j] + bias));
        }
      }
    }
  }
}

// ---------------- fallback (small workspace): fused f32, correct but slow --
__global__ __launch_bounds__(256) void naive_k(
    const float* __restrict__ x, const float* __restrict__ W_in,
    const float* __restrict__ b_in, const float* __restrict__ W_out,
    const float* __restrict__ b_out, const int* __restrict__ sel_e,
    const float* __restrict__ sel_w, float* __restrict__ out) {
  int s = blockIdx.x;
  int t = s >> 1;
  int e = sel_e[s];
  float w = sel_w[s];
  __shared__ float xs[DMODEL];
  __shared__ float hs[FFN];
  int tid = threadIdx.x;
  for (int d = tid; d < DMODEL; d += 256) xs[d] = x[(size_t)t * DMODEL + d];
  __syncthreads();
  for (int f = tid; f < FFN; f += 256) {
    float a = b_in[e * FFN + f];
    const float* wp = W_in + (size_t)e * DMODEL * FFN + f;
    for (int d = 0; d < DMODEL; d++) a += xs[d] * wp[(size_t)d * FFN];
    hs[f] = gelu_exact(a);
  }
  __syncthreads();
  for (int d = tid; d < DMODEL; d += 256) {
    float a = b_out[e * DMODEL + d];
    const float* wp = W_out + (size_t)e * FFN * DMODEL + d;
    for (int f = 0; f < FFN; f++) a += hs[f] * wp[(size_t)f * DMODEL];
    atomicAdd(&out[(size_t)t * DMODEL + d], w * a);
  }
}

extern "C" void kernel_launch(void* const* d_in, const int* in_sizes, int n_in,
                              void* d_out, int out_size, void* d_ws, size_t ws_size,
                              hipStream_t stream) {
  const float* residual = (const float*)d_in[0];
  const float* W_router = (const float*)d_in[1];
  const float* W_in = (const float*)d_in[2];
  const float* b_in = (const float*)d_in[3];
  const float* W_out = (const float*)d_in[4];
  const float* b_out = (const float*)d_in[5];
  float* out = (float*)d_out;

  char* ws = (char*)d_ws;
  int* meta = (int*)ws;  // 1 MB reserved for counters/schedule/lists
  size_t off = (size_t)1 << 20;
  f16* Xh = (f16*)(ws + off); off += (size_t)T_TOK * DMODEL * 2;       // 16 MB
  f16* Wih = (f16*)(ws + off); off += (size_t)NEXP * DMODEL * FFN * 2; // 64 MB
  f16* Woh = (f16*)(ws + off); off += (size_t)NEXP * DMODEL * FFN * 2; // 64 MB
  f16* H = (f16*)(ws + off); off += (size_t)NSLOT * FFN * 2;           // 128 MB
  bool fast = ws_size >= off;

  int* sel_e = meta + 1024;
  float* sel_w = (float*)(meta + 1024 + NSLOT);
  int* row_tok = meta + 1024 + 2 * NSLOT;
  float* row_w = (float*)(meta + 1024 + 3 * NSLOT);

  hipMemsetAsync(meta, 0, 4096, stream);                              // counts
  hipMemsetAsync(d_out, 0, (size_t)out_size * sizeof(float), stream); // output acc

  router_k<<<T_TOK / 4, 256, 0, stream>>>(residual, W_router, sel_e, sel_w, meta);

  if (fast) {
    cvtx_k<<<(T_TOK * DMODEL / 8) / 256, 256, 0, stream>>>(residual, Xh);
    transq_k<<<dim3(FFN / 32, DMODEL / 32, NEXP), 256, 0, stream>>>(W_in, Wih, DMODEL, FFN);
    transq_k<<<dim3(DMODEL / 32, FFN / 32, NEXP), 256, 0, stream>>>(W_out, Woh, FFN, DMODEL);
    sched_k<<<1, 1, 0, stream>>>(meta);
    scatter_k<<<NSLOT / 256, 256, 0, stream>>>(sel_e, sel_w, meta + 128, meta + 64,
                                               row_tok, row_w);
    gemm1_k<<<MAXT * (FFN / 128), 256, 0, stream>>>(Xh, Wih, b_in, H, meta);
    gemm2_k<<<MAXT * (DMODEL / 128), 256, 0, stream>>>(H, Woh, b_out, out, meta);
  } else {
    naive_k<<<NSLOT, 256, 0, stream>>>(residual, W_in, b_in, W_out, b_out,
                                       sel_e, sel_w, out);
  }
}